// Round 7
// baseline (375.611 us; speedup 1.0000x reference)
//
#include <hip/hip_runtime.h>
#include <cstdint>
#include <cstddef>

typedef __attribute__((ext_vector_type(8))) short bf16x8;   // 8 bf16 = 4 VGPR (MFMA A/B frag)
typedef __attribute__((ext_vector_type(4))) float f32x4;    // MFMA C/D frag

// ---------------- bf16 helpers ----------------

__device__ __forceinline__ unsigned short f2bf(float f) {  // RNE
    unsigned int u = __float_as_uint(f);
    u += 0x7FFFu + ((u >> 16) & 1u);
    return (unsigned short)(u >> 16);
}
__device__ __forceinline__ float bf2f(unsigned short h) {
    return __uint_as_float((unsigned int)h << 16);
}

// fma 8 bf16 (packed in uint4) * w into acc[8]
__device__ __forceinline__ void bf8_fma(uint4 u, float w, float* acc) {
    acc[0] += __uint_as_float(u.x << 16) * w;
    acc[1] += __uint_as_float(u.x & 0xFFFF0000u) * w;
    acc[2] += __uint_as_float(u.y << 16) * w;
    acc[3] += __uint_as_float(u.y & 0xFFFF0000u) * w;
    acc[4] += __uint_as_float(u.z << 16) * w;
    acc[5] += __uint_as_float(u.z & 0xFFFF0000u) * w;
    acc[6] += __uint_as_float(u.w << 16) * w;
    acc[7] += __uint_as_float(u.w & 0xFFFF0000u) * w;
}
__device__ __forceinline__ void bf8_unpack(uint4 u, float* v) {
    v[0] = __uint_as_float(u.x << 16);
    v[1] = __uint_as_float(u.x & 0xFFFF0000u);
    v[2] = __uint_as_float(u.y << 16);
    v[3] = __uint_as_float(u.y & 0xFFFF0000u);
    v[4] = __uint_as_float(u.z << 16);
    v[5] = __uint_as_float(u.z & 0xFFFF0000u);
    v[6] = __uint_as_float(u.w << 16);
    v[7] = __uint_as_float(u.w & 0xFFFF0000u);
}

// ---------------- R7 preprocessing: direct global-atomic CSR build ----------------
// The old slab pipeline (passA counting-sort -> bucket hist -> passB LDS scatter)
// had O(buckets) per-block fixed costs (scans, barriers, slab copies) that defeated
// both grid shapes tried (R5: 44us starved; R6: 62us overhead-bound). 2E global
// atomics to L2-resident counters cost ~10-20us/pass total -- cheaper than ANY
// slab schedule. Within-row order becomes atomic-nondeterministic (was already
// nondeterministic via passB's LDS atomics; tolerance covers it).

__global__ __launch_bounds__(256) void zero_hist(int* __restrict__ hist, int N4) {
    const int i = blockIdx.x * 256 + threadIdx.x;
    if (i < N4) ((int4*)hist)[i] = make_int4(0, 0, 0, 0);
}

__global__ __launch_bounds__(256) void hist_build(const int* __restrict__ dst,
                                                  int* __restrict__ hist, int E) {
    const int stride = gridDim.x * 256;
    for (int e = blockIdx.x * 256 + threadIdx.x; e < E; e += stride)
        atomicAdd(&hist[dst[e]], 1);
}

// exclusive scan of 8-PADDED degrees; dis folded in (first reader of final hist)

__global__ __launch_bounds__(256) void scan_partial(const int* __restrict__ hist,
                                                    int* __restrict__ partials,
                                                    float* __restrict__ dis, int N) {
    __shared__ int red[256];
    const int t    = threadIdx.x;
    const int base = blockIdx.x * 1024 + t * 4;
    int s = 0;
    if (base + 3 < N) {
        int4 v = *(const int4*)&hist[base];
        s = ((v.x + 7) & ~7) + ((v.y + 7) & ~7) + ((v.z + 7) & ~7) + ((v.w + 7) & ~7);
        dis[base]     = rsqrtf((float)(v.x + 1));  // +1 self loop
        dis[base + 1] = rsqrtf((float)(v.y + 1));
        dis[base + 2] = rsqrtf((float)(v.z + 1));
        dis[base + 3] = rsqrtf((float)(v.w + 1));
    } else {
        for (int i = 0; i < 4; i++)
            if (base + i < N) {
                int c = hist[base + i];
                s += (c + 7) & ~7;
                dis[base + i] = rsqrtf((float)(c + 1));
            }
    }
    red[t] = s;
    __syncthreads();
    for (int off = 128; off; off >>= 1) {
        if (t < off) red[t] += red[t + off];
        __syncthreads();
    }
    if (t == 0) partials[blockIdx.x] = red[0];
}

__global__ __launch_bounds__(256) void scan_offsets(int* __restrict__ partials, int NB) {
    __shared__ int tmp[256];
    const int t = threadIdx.x;
    int v = (t < NB) ? partials[t] : 0;
    tmp[t] = v;
    __syncthreads();
    for (int off = 1; off < 256; off <<= 1) {
        int u = (t >= off) ? tmp[t - off] : 0;
        __syncthreads();
        tmp[t] += u;
        __syncthreads();
    }
    if (t < NB) partials[t] = tmp[t] - v;
}

// writes ptr (row starts, 8-aligned) AND cur (scatter cursors, = ptr copy)

__global__ __launch_bounds__(256) void scan_apply(const int* __restrict__ hist,
                                                  const int* __restrict__ partials,
                                                  int* __restrict__ ptr,
                                                  int* __restrict__ cur, int N) {
    __shared__ int tsum[256];
    const int t    = threadIdx.x;
    const int base = blockIdx.x * 1024 + t * 4;
    int v[4];
    int s = 0;
    for (int i = 0; i < 4; i++) {
        int c = (base + i < N) ? hist[base + i] : 0;
        v[i]  = (c + 7) & ~7;
        s += v[i];
    }
    tsum[t] = s;
    __syncthreads();
    for (int off = 1; off < 256; off <<= 1) {
        int u = (t >= off) ? tsum[t - off] : 0;
        __syncthreads();
        tsum[t] += u;
        __syncthreads();
    }
    int run = partials[blockIdx.x] + tsum[t] - s;
    for (int i = 0; i < 4; i++) {
        if (base + i < N) {
            ptr[base + i] = run;
            cur[base + i] = run;
            run += v[i];
        }
    }
    if (base <= N - 1 && N - 1 < base + 4) ptr[N] = run;  // total = padded E
}

// pad slots (deg..pdeg, <=7 per row) = {0, 0.0f}: row-0 loads, fma x0 -- harmless

__global__ __launch_bounds__(256) void pad_fill(const int* __restrict__ hist,
                                                const int* __restrict__ ptr,
                                                int2* __restrict__ csrw, int N) {
    const int j = blockIdx.x * 256 + threadIdx.x;
    if (j >= N) return;
    const int t0 = ptr[j] + hist[j];
    const int t1 = ptr[j + 1];
    for (int p = t0; p < t1; ++p) csrw[p] = make_int2(0, 0);
}

// per-edge: slot = atomicAdd(cur[dst]); csrw[slot] = {src, dis[src]}

__global__ __launch_bounds__(256) void scatter_csr(const int* __restrict__ src,
                                                   const int* __restrict__ dst,
                                                   const float* __restrict__ dis,
                                                   int* __restrict__ cur,
                                                   int2* __restrict__ csrw, int E) {
    const int stride = gridDim.x * 256;
    for (int e = blockIdx.x * 256 + threadIdx.x; e < E; e += stride) {
        const int d = dst[e];
        const int s = src[e];
        const int p = atomicAdd(&cur[d], 1);
        csrw[p] = make_int2(s, __float_as_int(dis[s]));
    }
}

// ---------------- W fragment prep: fp32 W -> fragment-ordered bf16 hi/lo ----------
// B-frag layout for mfma_f32_16x16x32_bf16: lane&15 = out-col n, lane>>4 = k-octet,
// 8 contiguous k per lane. Stored so lane l of frag-block (kstep*4+nt) reads its
// 16 B contiguously at [(kstep*4+nt)*512 + l*8]. hi = RNE(w); lo = RNE(w - hi):
// Xhi*Whi + Xlo*Whi + Xhi*Wlo reproduces fp32 to ~2^-17 (lo*lo dropped).

__global__ __launch_bounds__(256) void prep_wfrag(const float* __restrict__ W1,
                                                  const float* __restrict__ W2,
                                                  unsigned short* __restrict__ whi1,
                                                  unsigned short* __restrict__ wlo1,
                                                  unsigned short* __restrict__ whi2,
                                                  unsigned short* __restrict__ wlo2) {
    for (int e = threadIdx.x; e < 128 * 64; e += 256) {
        const int blk = e >> 9, l = (e >> 3) & 63, j = e & 7;
        const int k = (blk >> 2) * 32 + (l >> 4) * 8 + j;
        const int n = (blk & 3) * 16 + (l & 15);
        const float v = W1[k * 64 + n];
        const unsigned short h = f2bf(v);
        whi1[e] = h;
        wlo1[e] = f2bf(v - bf2f(h));
    }
    for (int e = threadIdx.x; e < 64 * 64; e += 256) {
        const int blk = e >> 9, l = (e >> 3) & 63, j = e & 7;
        const int k = (blk >> 2) * 32 + (l >> 4) * 8 + j;
        const int n = (blk & 3) * 16 + (l & 15);
        const float v = W2[k * 64 + n];
        const unsigned short h = f2bf(v);
        whi2[e] = h;
        wlo2[e] = f2bf(v - bf2f(h));
    }
}

// ---------------- MFMA GEMM: Yb[N x 64](bf16) = X[N x K](f32) @ W[K x 64] ----------
// 64-row tile, 4 waves (wave w owns rows w*16..w*16+15). X staged fp32 into
// padded LDS (LDX=K+4 -> bank-balanced A-frag reads). A-frag: lane&15 = row m,
// lane>>4 = k-octet (8 contiguous k), split to bf16 hi/lo in-register. B-frags:
// coalesced 16 B/lane global loads from the prep arrays (48 KB, L2-hot).
// 3 MFMA per (kstep,ntile) = split-fp32 accuracy.
// C/D: col = lane&15, row = (lane>>4)*4 + reg [m89-verified mapping].

template <int K>
__global__ __launch_bounds__(256) void gemm_mfma(const float* __restrict__ X,
                                                 const unsigned short* __restrict__ whi,
                                                 const unsigned short* __restrict__ wlo,
                                                 unsigned short* __restrict__ Yb, int N) {
    constexpr int LDX = K + 4;
    __shared__ float xs[64 * LDX];
    const int tid  = threadIdx.x;
    const int row0 = blockIdx.x * 64;

#pragma unroll
    for (int i = 0; i < (64 * K) / 1024; ++i) {
        const int fidx = i * 1024 + tid * 4;
        const int r = fidx / K, c = fidx % K;
        const float4 v = *(const float4*)(X + (size_t)min(row0 + r, N - 1) * K + c);
        *(float4*)&xs[r * LDX + c] = v;
    }
    __syncthreads();

    const int w = tid >> 6, l = tid & 63;
    const int m = l & 15, kg = l >> 4;

    f32x4 acc[4] = {};
    const float* xrow = &xs[(w * 16 + m) * LDX];

#pragma unroll
    for (int s = 0; s < K / 32; ++s) {
        const float4 a0 = *(const float4*)(xrow + s * 32 + kg * 8);
        const float4 a1 = *(const float4*)(xrow + s * 32 + kg * 8 + 4);
        const float av[8] = {a0.x, a0.y, a0.z, a0.w, a1.x, a1.y, a1.z, a1.w};
        bf16x8 ahi, alo;
#pragma unroll
        for (int j = 0; j < 8; ++j) {
            const unsigned short h = f2bf(av[j]);
            ahi[j] = (short)h;
            alo[j] = (short)f2bf(av[j] - bf2f(h));
        }
#pragma unroll
        for (int nt = 0; nt < 4; ++nt) {
            const bf16x8 bh = *(const bf16x8*)&whi[(s * 4 + nt) * 512 + l * 8];
            const bf16x8 bl = *(const bf16x8*)&wlo[(s * 4 + nt) * 512 + l * 8];
            acc[nt] = __builtin_amdgcn_mfma_f32_16x16x32_bf16(ahi, bh, acc[nt], 0, 0, 0);
            acc[nt] = __builtin_amdgcn_mfma_f32_16x16x32_bf16(alo, bh, acc[nt], 0, 0, 0);
            acc[nt] = __builtin_amdgcn_mfma_f32_16x16x32_bf16(ahi, bl, acc[nt], 0, 0, 0);
        }
    }

#pragma unroll
    for (int nt = 0; nt < 4; ++nt)
#pragma unroll
        for (int r = 0; r < 4; ++r) {
            const int row = row0 + w * 16 + kg * 4 + r;
            if (row < N) Yb[(size_t)row * 64 + nt * 16 + m] = f2bf(acc[nt][r]);
        }
}

// ---------------- shuffle-free oct-row gather: 8 rows/wave, group-per-row ----------
// Row slabs are 8-padded (s0 % 8 == 0), so each lane loads its group's whole
// (src,w) chunk directly as 4 x int4 (64B, all 8 group lanes hit the same L1
// lines -> broadcast). No ds_bpermute, no bounds predication in the loop.
// Next chunk is prefetched one iteration ahead; 8 independent B-row loads are
// in flight per lane per iteration. Groups exit independently (divergence safe).

__device__ __forceinline__ void gather8_pad(const unsigned short* __restrict__ B,
                                            const int2* __restrict__ csrw,
                                            int s0, int iters, int co, float* acc) {
    const int4* cs = (const int4*)(csrw + s0);  // 64B-aligned (s0 % 8 == 0)
    int4 c0 = make_int4(0, 0, 0, 0), c1 = c0, c2 = c0, c3 = c0;
    if (iters > 0) { c0 = cs[0]; c1 = cs[1]; c2 = cs[2]; c3 = cs[3]; }
    for (int it = 0; it < iters; ++it) {
        const int nb = min(it + 1, iters - 1) * 4;   // prefetch next chunk (clamped)
        int4 n0 = cs[nb], n1 = cs[nb + 1], n2 = cs[nb + 2], n3 = cs[nb + 3];
        uint4 u0 = *(const uint4*)&B[(size_t)c0.x * 64 + co * 8];
        uint4 u1 = *(const uint4*)&B[(size_t)c0.z * 64 + co * 8];
        uint4 u2 = *(const uint4*)&B[(size_t)c1.x * 64 + co * 8];
        uint4 u3 = *(const uint4*)&B[(size_t)c1.z * 64 + co * 8];
        uint4 u4 = *(const uint4*)&B[(size_t)c2.x * 64 + co * 8];
        uint4 u5 = *(const uint4*)&B[(size_t)c2.z * 64 + co * 8];
        uint4 u6 = *(const uint4*)&B[(size_t)c3.x * 64 + co * 8];
        uint4 u7 = *(const uint4*)&B[(size_t)c3.z * 64 + co * 8];
        bf8_fma(u0, __int_as_float(c0.y), acc);
        bf8_fma(u1, __int_as_float(c0.w), acc);
        bf8_fma(u2, __int_as_float(c1.y), acc);
        bf8_fma(u3, __int_as_float(c1.w), acc);
        bf8_fma(u4, __int_as_float(c2.y), acc);
        bf8_fma(u5, __int_as_float(c2.w), acc);
        bf8_fma(u6, __int_as_float(c3.y), acc);
        bf8_fma(u7, __int_as_float(c3.w), acc);
        c0 = n0; c1 = n1; c2 = n2; c3 = n3;
    }
}

// ---------------- layer 1: pure gather + relu -> f32 h (scratch = d_out) -----------

__global__ __launch_bounds__(256) void agg_l1(const unsigned short* __restrict__ B,
                                              const int2* __restrict__ csrw,
                                              const int* __restrict__ ptr,
                                              const float* __restrict__ dis,
                                              const float* __restrict__ b1,
                                              float* __restrict__ hs, int N) {
    const int wid  = threadIdx.x >> 6;
    const int lane = threadIdx.x & 63;
    const int eg   = lane >> 3;
    const int co   = lane & 7;

    const int  row = blockIdx.x * 32 + wid * 8 + eg;   // group eg owns this row
    const bool hr  = (row < N);

    const int   s0 = hr ? ptr[row] : 0;
    const int   s1 = hr ? ptr[row + 1] : 0;
    const float di = hr ? dis[row] : 0.f;
    const int   iters = (s1 - s0) >> 3;   // slabs are 8-padded

    float acc[8] = {};
    gather8_pad(B, csrw, s0, iters, co, acc);

    if (!hr) return;

    uint4 us = *(const uint4*)&B[(size_t)row * 64 + co * 8];
    float bs[8];
    bf8_unpack(us, bs);
    float bb[8];
    *(float4*)&bb[0] = *(const float4*)&b1[co * 8];
    *(float4*)&bb[4] = *(const float4*)&b1[co * 8 + 4];

    float h[8];
#pragma unroll
    for (int i = 0; i < 8; i++)
        h[i] = fmaxf((acc[i] + bs[i] * di) * di + bb[i], 0.f);

    *(float4*)&hs[(size_t)row * 64 + co * 8]     = make_float4(h[0], h[1], h[2], h[3]);
    *(float4*)&hs[(size_t)row * 64 + co * 8 + 4] = make_float4(h[4], h[5], h[6], h[7]);
}

// ---------------- layer 2: gather h2 + bias + log_softmax -> fp32 out --------------

__global__ __launch_bounds__(256) void agg_l2(const unsigned short* __restrict__ B,
                                              const int2* __restrict__ csrw,
                                              const int* __restrict__ ptr,
                                              const float* __restrict__ dis,
                                              const float* __restrict__ b2,
                                              float* __restrict__ out, int N) {
    const int wid  = threadIdx.x >> 6;
    const int lane = threadIdx.x & 63;
    const int eg   = lane >> 3;
    const int co   = lane & 7;

    const int  row = blockIdx.x * 32 + wid * 8 + eg;
    const bool hr  = (row < N);

    const int   s0 = hr ? ptr[row] : 0;
    const int   s1 = hr ? ptr[row + 1] : 0;
    const float di = hr ? dis[row] : 0.f;
    const int   iters = (s1 - s0) >> 3;

    float acc[8] = {};
    gather8_pad(B, csrw, s0, iters, co, acc);

    if (!hr) return;

    uint4 us = *(const uint4*)&B[(size_t)row * 64 + co * 8];
    float bs[8];
    bf8_unpack(us, bs);
    float bb[8];
    *(float4*)&bb[0] = *(const float4*)&b2[co * 8];
    *(float4*)&bb[4] = *(const float4*)&b2[co * 8 + 4];

    float v[8];
#pragma unroll
    for (int i = 0; i < 8; i++) v[i] = (acc[i] + bs[i] * di) * di + bb[i];

    float m = v[0];
#pragma unroll
    for (int i = 1; i < 8; i++) m = fmaxf(m, v[i]);
#pragma unroll
    for (int off = 1; off <= 4; off <<= 1) m = fmaxf(m, __shfl_xor(m, off));
    float s = 0.f;
#pragma unroll
    for (int i = 0; i < 8; i++) s += __expf(v[i] - m);
#pragma unroll
    for (int off = 1; off <= 4; off <<= 1) s += __shfl_xor(s, off);
    float lse = m + __logf(s);

    float4 oa = make_float4(v[0] - lse, v[1] - lse, v[2] - lse, v[3] - lse);
    float4 ob = make_float4(v[4] - lse, v[5] - lse, v[6] - lse, v[7] - lse);
    *(float4*)&out[(size_t)row * 64 + co * 8]     = oa;
    *(float4*)&out[(size_t)row * 64 + co * 8 + 4] = ob;
}

// ---------------- launch ----------------

extern "C" void kernel_launch(void* const* d_in, const int* in_sizes, int n_in,
                              void* d_out, int out_size, void* d_ws, size_t ws_size,
                              hipStream_t stream) {
    const float* x   = (const float*)d_in[0];
    const int*   ei  = (const int*)d_in[1];
    const float* W1  = (const float*)d_in[2];
    const float* b1  = (const float*)d_in[3];
    const float* W2  = (const float*)d_in[4];
    const float* b2  = (const float*)d_in[5];
    float*       out = (float*)d_out;

    const int  N   = in_sizes[0] / 128;
    const int  E   = in_sizes[1] / 2;
    const int* src = ei;
    const int* dst = ei + E;
    const int  NB  = (N + 1023) / 1024;
    const int  N4  = (N + 3) / 4;
    const int  EB  = min((E + 255) / 256, 2048);

    auto align256 = [](size_t v) { return (v + 255) & ~(size_t)255; };
    char*           p        = (char*)d_ws;
    float*          dis      = (float*)p;          p += align256((size_t)N * 4);
    int*            ptr      = (int*)p;            p += align256((size_t)(N + 1) * 4);
    int*            hist     = (int*)p;            p += align256((size_t)N * 4);
    int*            cur      = (int*)p;            p += align256((size_t)N * 4);
    int*            partials = (int*)p;            p += align256((size_t)NB * 4);
    int2*           csrw     = (int2*)p;           p += align256(((size_t)E + 8 * (size_t)N) * 8);
    unsigned short* xwb      = (unsigned short*)p; p += align256((size_t)N * 64 * 2);
    unsigned short* whi1     = (unsigned short*)p; p += align256(128 * 64 * 2);
    unsigned short* wlo1     = (unsigned short*)p; p += align256(128 * 64 * 2);
    unsigned short* whi2     = (unsigned short*)p; p += align256(64 * 64 * 2);
    unsigned short* wlo2     = (unsigned short*)p; p += align256(64 * 64 * 2);

    // h (post-relu, f32) scratch lives in d_out: dead until agg_l2 overwrites it.
    float* hs = out;

    zero_hist<<<(N4 + 255) / 256, 256, 0, stream>>>(hist, N4);
    prep_wfrag<<<1, 256, 0, stream>>>(W1, W2, whi1, wlo1, whi2, wlo2);
    hist_build<<<EB, 256, 0, stream>>>(dst, hist, E);
    scan_partial<<<NB, 256, 0, stream>>>(hist, partials, dis, N);
    scan_offsets<<<1, 256, 0, stream>>>(partials, NB);
    scan_apply<<<NB, 256, 0, stream>>>(hist, partials, ptr, cur, N);
    pad_fill<<<(N + 255) / 256, 256, 0, stream>>>(hist, ptr, csrw, N);
    scatter_csr<<<EB, 256, 0, stream>>>(src, dst, dis, cur, csrw, E);

    gemm_mfma<128><<<(N + 63) / 64, 256, 0, stream>>>(x, whi1, wlo1, xwb, N);
    agg_l1<<<(N + 31) / 32, 256, 0, stream>>>(xwb, csrw, ptr, dis, b1, hs, N);
    // gemm2: h2(bf16, reuses dead xwb) = h(f32, in d_out) @ W2
    gemm_mfma<64><<<(N + 63) / 64, 256, 0, stream>>>(hs, whi2, wlo2, xwb, N);
    agg_l2<<<(N + 31) / 32, 256, 0, stream>>>(xwb, csrw, ptr, dis, b2, out, N);
}

// Round 8
// 268.963 us; speedup vs baseline: 1.3965x; 1.3965x over previous
//
#include <hip/hip_runtime.h>
#include <cstdint>
#include <cstddef>

#define PASSA_EDGES 2048

typedef __attribute__((ext_vector_type(8))) short bf16x8;   // 8 bf16 = 4 VGPR (MFMA A/B frag)
typedef __attribute__((ext_vector_type(4))) float f32x4;    // MFMA C/D frag

// ---------------- bf16 helpers ----------------

__device__ __forceinline__ unsigned short f2bf(float f) {  // RNE
    unsigned int u = __float_as_uint(f);
    u += 0x7FFFu + ((u >> 16) & 1u);
    return (unsigned short)(u >> 16);
}
__device__ __forceinline__ float bf2f(unsigned short h) {
    return __uint_as_float((unsigned int)h << 16);
}

// fma 8 bf16 (packed in uint4) * w into acc[8]
__device__ __forceinline__ void bf8_fma(uint4 u, float w, float* acc) {
    acc[0] += __uint_as_float(u.x << 16) * w;
    acc[1] += __uint_as_float(u.x & 0xFFFF0000u) * w;
    acc[2] += __uint_as_float(u.y << 16) * w;
    acc[3] += __uint_as_float(u.y & 0xFFFF0000u) * w;
    acc[4] += __uint_as_float(u.z << 16) * w;
    acc[5] += __uint_as_float(u.z & 0xFFFF0000u) * w;
    acc[6] += __uint_as_float(u.w << 16) * w;
    acc[7] += __uint_as_float(u.w & 0xFFFF0000u) * w;
}
__device__ __forceinline__ void bf8_unpack(uint4 u, float* v) {
    v[0] = __uint_as_float(u.x << 16);
    v[1] = __uint_as_float(u.x & 0xFFFF0000u);
    v[2] = __uint_as_float(u.y << 16);
    v[3] = __uint_as_float(u.y & 0xFFFF0000u);
    v[4] = __uint_as_float(u.z << 16);
    v[5] = __uint_as_float(u.z & 0xFFFF0000u);
    v[6] = __uint_as_float(u.w << 16);
    v[7] = __uint_as_float(u.w & 0xFFFF0000u);
}

// ---------------- bucket cursor init ----------------

__global__ void bcur_init(int* __restrict__ bcur, int NBUCK, int CAP) {
    int b = threadIdx.x;
    if (b < NBUCK) bcur[b] = b * CAP;
}

// ---------------- pass A v2: scan-free bin into slabs (direct scatter) -------------
// R8: per 2048-edge block: LDS histogram -> slab range reservation -> re-read edges
// and scatter straight to bbuf. No bins image, no prefix scan, no per-bucket
// writeout loop (R6's O(buckets) fixed costs gone; LDS 3 KB -> full occupancy).
// Each block's writes land in 256 contiguous sub-ranges of the slabs -> full
// cache lines assemble in L2, no write amplification (R7's 5x lesson).

__global__ __launch_bounds__(256) void passA(const int* __restrict__ src,
                                             const int* __restrict__ dst,
                                             int* __restrict__ bcur,
                                             int2* __restrict__ bbuf, int E,
                                             int CAP, int shift) {
    __shared__ int cnt[256], cur[256];
    const int t  = threadIdx.x;
    const int e0 = blockIdx.x * PASSA_EDGES;
    const int n  = min(PASSA_EDGES, E - e0);

    cnt[t] = 0;
    __syncthreads();
    for (int i = t; i < n; i += 256) atomicAdd(&cnt[dst[e0 + i] >> shift], 1);
    __syncthreads();

    const int c = cnt[t];
    cur[t] = (c > 0) ? atomicAdd(&bcur[t], c) : 0;
    __syncthreads();

    for (int i = t; i < n; i += 256) {
        const int d = dst[e0 + i];
        const int s = src[e0 + i];
        const int b = d >> shift;
        const int p = atomicAdd(&cur[b], 1);
        if (p < (b + 1) * CAP) bbuf[p] = make_int2(s, d);  // slab-overflow guard
    }
}

// ---------------- per-bucket histogram: TRUE degree (padding applied in scan) ------

__global__ __launch_bounds__(256) void hist_dis(const int2* __restrict__ bbuf,
                                                const int* __restrict__ bcur,
                                                int* __restrict__ hist,
                                                int N, int CAP, int shift) {
    __shared__ int cnt[1024];
    const int b     = blockIdx.x;
    const int node0 = b << shift;
    const int nn    = min(1 << shift, N - node0);
    for (int j = threadIdx.x; j < nn; j += 256) cnt[j] = 0;
    __syncthreads();
    const int start = b * CAP;
    const int end   = min(bcur[b], (b + 1) * CAP);
    for (int e = start + threadIdx.x; e < end; e += 256)
        atomicAdd(&cnt[bbuf[e].y - node0], 1);
    __syncthreads();
    for (int j = threadIdx.x; j < nn; j += 256) hist[node0 + j] = cnt[j];
}

// ---------------- 3-phase exclusive scan of 8-PADDED degrees; dis folded in --------

__global__ __launch_bounds__(256) void scan_partial(const int* __restrict__ hist,
                                                    int* __restrict__ partials,
                                                    float* __restrict__ dis, int N) {
    __shared__ int red[256];
    const int t    = threadIdx.x;
    const int base = blockIdx.x * 1024 + t * 4;
    int s = 0;
    if (base + 3 < N) {
        int4 v = *(const int4*)&hist[base];
        s = ((v.x + 7) & ~7) + ((v.y + 7) & ~7) + ((v.z + 7) & ~7) + ((v.w + 7) & ~7);
        dis[base]     = rsqrtf((float)(v.x + 1));  // +1 self loop
        dis[base + 1] = rsqrtf((float)(v.y + 1));
        dis[base + 2] = rsqrtf((float)(v.z + 1));
        dis[base + 3] = rsqrtf((float)(v.w + 1));
    } else {
        for (int i = 0; i < 4; i++)
            if (base + i < N) {
                int c = hist[base + i];
                s += (c + 7) & ~7;
                dis[base + i] = rsqrtf((float)(c + 1));
            }
    }
    red[t] = s;
    __syncthreads();
    for (int off = 128; off; off >>= 1) {
        if (t < off) red[t] += red[t + off];
        __syncthreads();
    }
    if (t == 0) partials[blockIdx.x] = red[0];
}

__global__ __launch_bounds__(256) void scan_offsets(int* __restrict__ partials, int NB) {
    __shared__ int tmp[256];
    const int t = threadIdx.x;
    int v = (t < NB) ? partials[t] : 0;
    tmp[t] = v;
    __syncthreads();
    for (int off = 1; off < 256; off <<= 1) {
        int u = (t >= off) ? tmp[t - off] : 0;
        __syncthreads();
        tmp[t] += u;
        __syncthreads();
    }
    if (t < NB) partials[t] = tmp[t] - v;
}

__global__ __launch_bounds__(256) void scan_apply(const int* __restrict__ hist,
                                                  const int* __restrict__ partials,
                                                  int* __restrict__ ptr, int N) {
    __shared__ int tsum[256];
    const int t    = threadIdx.x;
    const int base = blockIdx.x * 1024 + t * 4;
    int v[4];
    int s = 0;
    for (int i = 0; i < 4; i++) {
        int c = (base + i < N) ? hist[base + i] : 0;
        v[i]  = (c + 7) & ~7;
        s += v[i];
    }
    tsum[t] = s;
    __syncthreads();
    for (int off = 1; off < 256; off <<= 1) {
        int u = (t >= off) ? tsum[t - off] : 0;
        __syncthreads();
        tsum[t] += u;
        __syncthreads();
    }
    int run = partials[blockIdx.x] + tsum[t] - s;
    for (int i = 0; i < 4; i++) {
        if (base + i < N) {
            ptr[base + i] = run;
            run += v[i];
        }
    }
    if (base <= N - 1 && N - 1 < base + 4) ptr[N] = run;  // total = padded E
}

// pad slots (deg..pdeg, <=7 per row) = {0, 0.0f}: row-0 loads, fma x0 -- harmless

__global__ __launch_bounds__(256) void pad_fill(const int* __restrict__ hist,
                                                const int* __restrict__ ptr,
                                                int2* __restrict__ csrw, int N) {
    const int j = blockIdx.x * 256 + threadIdx.x;
    if (j >= N) return;
    const int t0 = ptr[j] + hist[j];
    const int t1 = ptr[j + 1];
    for (int p = t0; p < t1; ++p) csrw[p] = make_int2(0, 0);
}

// ---------------- pass B v2: image-free per-bucket scatter -> (src,w) csr ----------
// LDS node-cursors seeded from ptr; direct global writes land inside the bucket's
// ~100 KB contiguous csrw window (row sub-ranges dense) -> L2 assembles full
// lines, no amplification. No lcsr image, no -1 fill, no CAP fallback branch.

__global__ __launch_bounds__(256) void passB(const int2* __restrict__ bbuf,
                                             const int* __restrict__ bcur,
                                             const int* __restrict__ ptr,
                                             int2* __restrict__ csrw,
                                             const float* __restrict__ dis,
                                             int N, int CAP, int shift) {
    __shared__ int lcur[1024];
    const int b     = blockIdx.x;
    const int node0 = b << shift;
    const int nn    = min(1 << shift, N - node0);
    for (int j = threadIdx.x; j < nn; j += 256) lcur[j] = ptr[node0 + j];
    __syncthreads();

    const int start = b * CAP;
    const int end   = min(bcur[b], (b + 1) * CAP);
    for (int e = start + threadIdx.x; e < end; e += 256) {
        const int2 pr = bbuf[e];
        const int  p  = atomicAdd(&lcur[pr.y - node0], 1);
        csrw[p] = make_int2(pr.x, __float_as_int(dis[pr.x]));
    }
}

// ---------------- W fragment prep: fp32 W -> fragment-ordered bf16 hi/lo ----------
// B-frag layout for mfma_f32_16x16x32_bf16: lane&15 = out-col n, lane>>4 = k-octet,
// 8 contiguous k per lane. Stored so lane l of frag-block (kstep*4+nt) reads its
// 16 B contiguously at [(kstep*4+nt)*512 + l*8]. hi = RNE(w); lo = RNE(w - hi):
// Xhi*Whi + Xlo*Whi + Xhi*Wlo reproduces fp32 to ~2^-17 (lo*lo dropped).

__global__ __launch_bounds__(256) void prep_wfrag(const float* __restrict__ W1,
                                                  const float* __restrict__ W2,
                                                  unsigned short* __restrict__ whi1,
                                                  unsigned short* __restrict__ wlo1,
                                                  unsigned short* __restrict__ whi2,
                                                  unsigned short* __restrict__ wlo2) {
    for (int e = threadIdx.x; e < 128 * 64; e += 256) {
        const int blk = e >> 9, l = (e >> 3) & 63, j = e & 7;
        const int k = (blk >> 2) * 32 + (l >> 4) * 8 + j;
        const int n = (blk & 3) * 16 + (l & 15);
        const float v = W1[k * 64 + n];
        const unsigned short h = f2bf(v);
        whi1[e] = h;
        wlo1[e] = f2bf(v - bf2f(h));
    }
    for (int e = threadIdx.x; e < 64 * 64; e += 256) {
        const int blk = e >> 9, l = (e >> 3) & 63, j = e & 7;
        const int k = (blk >> 2) * 32 + (l >> 4) * 8 + j;
        const int n = (blk & 3) * 16 + (l & 15);
        const float v = W2[k * 64 + n];
        const unsigned short h = f2bf(v);
        whi2[e] = h;
        wlo2[e] = f2bf(v - bf2f(h));
    }
}

// ---------------- MFMA GEMM: Yb[N x 64](bf16) = X[N x K](f32) @ W[K x 64] ----------
// 64-row tile, 4 waves (wave w owns rows w*16..w*16+15). X staged fp32 into
// padded LDS (LDX=K+4 -> bank-balanced A-frag reads). A-frag: lane&15 = row m,
// lane>>4 = k-octet (8 contiguous k), split to bf16 hi/lo in-register. B-frags:
// coalesced 16 B/lane global loads from the prep arrays (48 KB, L2-hot).
// 3 MFMA per (kstep,ntile) = split-fp32 accuracy.
// C/D: col = lane&15, row = (lane>>4)*4 + reg [m89-verified mapping].

template <int K>
__global__ __launch_bounds__(256) void gemm_mfma(const float* __restrict__ X,
                                                 const unsigned short* __restrict__ whi,
                                                 const unsigned short* __restrict__ wlo,
                                                 unsigned short* __restrict__ Yb, int N) {
    constexpr int LDX = K + 4;
    __shared__ float xs[64 * LDX];
    const int tid  = threadIdx.x;
    const int row0 = blockIdx.x * 64;

#pragma unroll
    for (int i = 0; i < (64 * K) / 1024; ++i) {
        const int fidx = i * 1024 + tid * 4;
        const int r = fidx / K, c = fidx % K;
        const float4 v = *(const float4*)(X + (size_t)min(row0 + r, N - 1) * K + c);
        *(float4*)&xs[r * LDX + c] = v;
    }
    __syncthreads();

    const int w = tid >> 6, l = tid & 63;
    const int m = l & 15, kg = l >> 4;

    f32x4 acc[4] = {};
    const float* xrow = &xs[(w * 16 + m) * LDX];

#pragma unroll
    for (int s = 0; s < K / 32; ++s) {
        const float4 a0 = *(const float4*)(xrow + s * 32 + kg * 8);
        const float4 a1 = *(const float4*)(xrow + s * 32 + kg * 8 + 4);
        const float av[8] = {a0.x, a0.y, a0.z, a0.w, a1.x, a1.y, a1.z, a1.w};
        bf16x8 ahi, alo;
#pragma unroll
        for (int j = 0; j < 8; ++j) {
            const unsigned short h = f2bf(av[j]);
            ahi[j] = (short)h;
            alo[j] = (short)f2bf(av[j] - bf2f(h));
        }
#pragma unroll
        for (int nt = 0; nt < 4; ++nt) {
            const bf16x8 bh = *(const bf16x8*)&whi[(s * 4 + nt) * 512 + l * 8];
            const bf16x8 bl = *(const bf16x8*)&wlo[(s * 4 + nt) * 512 + l * 8];
            acc[nt] = __builtin_amdgcn_mfma_f32_16x16x32_bf16(ahi, bh, acc[nt], 0, 0, 0);
            acc[nt] = __builtin_amdgcn_mfma_f32_16x16x32_bf16(alo, bh, acc[nt], 0, 0, 0);
            acc[nt] = __builtin_amdgcn_mfma_f32_16x16x32_bf16(ahi, bl, acc[nt], 0, 0, 0);
        }
    }

#pragma unroll
    for (int nt = 0; nt < 4; ++nt)
#pragma unroll
        for (int r = 0; r < 4; ++r) {
            const int row = row0 + w * 16 + kg * 4 + r;
            if (row < N) Yb[(size_t)row * 64 + nt * 16 + m] = f2bf(acc[nt][r]);
        }
}

// ---------------- shuffle-free oct-row gather: 8 rows/wave, group-per-row ----------
// Row slabs are 8-padded (s0 % 8 == 0), so each lane loads its group's whole
// (src,w) chunk directly as 4 x int4 (64B, all 8 group lanes hit the same L1
// lines -> broadcast). No ds_bpermute, no bounds predication in the loop.
// Next chunk is prefetched one iteration ahead; 8 independent B-row loads are
// in flight per lane per iteration. Groups exit independently (divergence safe).

__device__ __forceinline__ void gather8_pad(const unsigned short* __restrict__ B,
                                            const int2* __restrict__ csrw,
                                            int s0, int iters, int co, float* acc) {
    const int4* cs = (const int4*)(csrw + s0);  // 64B-aligned (s0 % 8 == 0)
    int4 c0 = make_int4(0, 0, 0, 0), c1 = c0, c2 = c0, c3 = c0;
    if (iters > 0) { c0 = cs[0]; c1 = cs[1]; c2 = cs[2]; c3 = cs[3]; }
    for (int it = 0; it < iters; ++it) {
        const int nb = min(it + 1, iters - 1) * 4;   // prefetch next chunk (clamped)
        int4 n0 = cs[nb], n1 = cs[nb + 1], n2 = cs[nb + 2], n3 = cs[nb + 3];
        uint4 u0 = *(const uint4*)&B[(size_t)c0.x * 64 + co * 8];
        uint4 u1 = *(const uint4*)&B[(size_t)c0.z * 64 + co * 8];
        uint4 u2 = *(const uint4*)&B[(size_t)c1.x * 64 + co * 8];
        uint4 u3 = *(const uint4*)&B[(size_t)c1.z * 64 + co * 8];
        uint4 u4 = *(const uint4*)&B[(size_t)c2.x * 64 + co * 8];
        uint4 u5 = *(const uint4*)&B[(size_t)c2.z * 64 + co * 8];
        uint4 u6 = *(const uint4*)&B[(size_t)c3.x * 64 + co * 8];
        uint4 u7 = *(const uint4*)&B[(size_t)c3.z * 64 + co * 8];
        bf8_fma(u0, __int_as_float(c0.y), acc);
        bf8_fma(u1, __int_as_float(c0.w), acc);
        bf8_fma(u2, __int_as_float(c1.y), acc);
        bf8_fma(u3, __int_as_float(c1.w), acc);
        bf8_fma(u4, __int_as_float(c2.y), acc);
        bf8_fma(u5, __int_as_float(c2.w), acc);
        bf8_fma(u6, __int_as_float(c3.y), acc);
        bf8_fma(u7, __int_as_float(c3.w), acc);
        c0 = n0; c1 = n1; c2 = n2; c3 = n3;
    }
}

// ---------------- layer 1: pure gather + relu -> f32 h (scratch = d_out) -----------

__global__ __launch_bounds__(256) void agg_l1(const unsigned short* __restrict__ B,
                                              const int2* __restrict__ csrw,
                                              const int* __restrict__ ptr,
                                              const float* __restrict__ dis,
                                              const float* __restrict__ b1,
                                              float* __restrict__ hs, int N) {
    const int wid  = threadIdx.x >> 6;
    const int lane = threadIdx.x & 63;
    const int eg   = lane >> 3;
    const int co   = lane & 7;

    const int  row = blockIdx.x * 32 + wid * 8 + eg;   // group eg owns this row
    const bool hr  = (row < N);

    const int   s0 = hr ? ptr[row] : 0;
    const int   s1 = hr ? ptr[row + 1] : 0;
    const float di = hr ? dis[row] : 0.f;
    const int   iters = (s1 - s0) >> 3;   // slabs are 8-padded

    float acc[8] = {};
    gather8_pad(B, csrw, s0, iters, co, acc);

    if (!hr) return;

    uint4 us = *(const uint4*)&B[(size_t)row * 64 + co * 8];
    float bs[8];
    bf8_unpack(us, bs);
    float bb[8];
    *(float4*)&bb[0] = *(const float4*)&b1[co * 8];
    *(float4*)&bb[4] = *(const float4*)&b1[co * 8 + 4];

    float h[8];
#pragma unroll
    for (int i = 0; i < 8; i++)
        h[i] = fmaxf((acc[i] + bs[i] * di) * di + bb[i], 0.f);

    *(float4*)&hs[(size_t)row * 64 + co * 8]     = make_float4(h[0], h[1], h[2], h[3]);
    *(float4*)&hs[(size_t)row * 64 + co * 8 + 4] = make_float4(h[4], h[5], h[6], h[7]);
}

// ---------------- layer 2: gather h2 + bias + log_softmax -> fp32 out --------------

__global__ __launch_bounds__(256) void agg_l2(const unsigned short* __restrict__ B,
                                              const int2* __restrict__ csrw,
                                              const int* __restrict__ ptr,
                                              const float* __restrict__ dis,
                                              const float* __restrict__ b2,
                                              float* __restrict__ out, int N) {
    const int wid  = threadIdx.x >> 6;
    const int lane = threadIdx.x & 63;
    const int eg   = lane >> 3;
    const int co   = lane & 7;

    const int  row = blockIdx.x * 32 + wid * 8 + eg;
    const bool hr  = (row < N);

    const int   s0 = hr ? ptr[row] : 0;
    const int   s1 = hr ? ptr[row + 1] : 0;
    const float di = hr ? dis[row] : 0.f;
    const int   iters = (s1 - s0) >> 3;

    float acc[8] = {};
    gather8_pad(B, csrw, s0, iters, co, acc);

    if (!hr) return;

    uint4 us = *(const uint4*)&B[(size_t)row * 64 + co * 8];
    float bs[8];
    bf8_unpack(us, bs);
    float bb[8];
    *(float4*)&bb[0] = *(const float4*)&b2[co * 8];
    *(float4*)&bb[4] = *(const float4*)&b2[co * 8 + 4];

    float v[8];
#pragma unroll
    for (int i = 0; i < 8; i++) v[i] = (acc[i] + bs[i] * di) * di + bb[i];

    float m = v[0];
#pragma unroll
    for (int i = 1; i < 8; i++) m = fmaxf(m, v[i]);
#pragma unroll
    for (int off = 1; off <= 4; off <<= 1) m = fmaxf(m, __shfl_xor(m, off));
    float s = 0.f;
#pragma unroll
    for (int i = 0; i < 8; i++) s += __expf(v[i] - m);
#pragma unroll
    for (int off = 1; off <= 4; off <<= 1) s += __shfl_xor(s, off);
    float lse = m + __logf(s);

    float4 oa = make_float4(v[0] - lse, v[1] - lse, v[2] - lse, v[3] - lse);
    float4 ob = make_float4(v[4] - lse, v[5] - lse, v[6] - lse, v[7] - lse);
    *(float4*)&out[(size_t)row * 64 + co * 8]     = oa;
    *(float4*)&out[(size_t)row * 64 + co * 8 + 4] = ob;
}

// ---------------- launch ----------------

extern "C" void kernel_launch(void* const* d_in, const int* in_sizes, int n_in,
                              void* d_out, int out_size, void* d_ws, size_t ws_size,
                              hipStream_t stream) {
    const float* x   = (const float*)d_in[0];
    const int*   ei  = (const int*)d_in[1];
    const float* W1  = (const float*)d_in[2];
    const float* b1  = (const float*)d_in[3];
    const float* W2  = (const float*)d_in[4];
    const float* b2  = (const float*)d_in[5];
    float*       out = (float*)d_out;

    const int  N   = in_sizes[0] / 128;
    const int  E   = in_sizes[1] / 2;
    const int* src = ei;
    const int* dst = ei + E;
    const int  NB  = (N + 1023) / 1024;

    int shift = 9;
    while (((N - 1) >> shift) >= 256) shift++;
    const int NBUCK = ((N - 1) >> shift) + 1;
    const int CAP   = ((E / NBUCK) * 3 / 2 + 255) & ~255;

    auto align256 = [](size_t v) { return (v + 255) & ~(size_t)255; };
    char*           p        = (char*)d_ws;
    float*          dis      = (float*)p;          p += align256((size_t)N * 4);
    int*            ptr      = (int*)p;            p += align256((size_t)(N + 1) * 4);
    int*            hist     = (int*)p;            p += align256((size_t)N * 4);
    int*            partials = (int*)p;            p += align256((size_t)NB * 4);
    int*            bcur     = (int*)p;            p += align256(256 * 4);
    int2*           csrw     = (int2*)p;           p += align256(((size_t)E + 8 * (size_t)N) * 8);
    int2*           bbuf     = (int2*)p;           p += align256((size_t)NBUCK * CAP * 8);
    unsigned short* xwb      = (unsigned short*)p; p += align256((size_t)N * 64 * 2);
    unsigned short* whi1     = (unsigned short*)p; p += align256(128 * 64 * 2);
    unsigned short* wlo1     = (unsigned short*)p; p += align256(128 * 64 * 2);
    unsigned short* whi2     = (unsigned short*)p; p += align256(64 * 64 * 2);
    unsigned short* wlo2     = (unsigned short*)p; p += align256(64 * 64 * 2);

    // h (post-relu, f32) scratch lives in d_out: dead until agg_l2 overwrites it.
    float* hs = out;

    bcur_init<<<1, 256, 0, stream>>>(bcur, NBUCK, CAP);
    prep_wfrag<<<1, 256, 0, stream>>>(W1, W2, whi1, wlo1, whi2, wlo2);
    passA<<<(E + PASSA_EDGES - 1) / PASSA_EDGES, 256, 0, stream>>>(src, dst, bcur, bbuf, E, CAP, shift);
    hist_dis<<<NBUCK, 256, 0, stream>>>(bbuf, bcur, hist, N, CAP, shift);
    scan_partial<<<NB, 256, 0, stream>>>(hist, partials, dis, N);
    scan_offsets<<<1, 256, 0, stream>>>(partials, NB);
    scan_apply<<<NB, 256, 0, stream>>>(hist, partials, ptr, N);
    pad_fill<<<(N + 255) / 256, 256, 0, stream>>>(hist, ptr, csrw, N);
    passB<<<NBUCK, 256, 0, stream>>>(bbuf, bcur, ptr, csrw, dis, N, CAP, shift);

    gemm_mfma<128><<<(N + 63) / 64, 256, 0, stream>>>(x, whi1, wlo1, xwb, N);
    agg_l1<<<(N + 31) / 32, 256, 0, stream>>>(xwb, csrw, ptr, dis, b1, hs, N);
    // gemm2: h2(bf16, reuses dead xwb) = h(f32, in d_out) @ W2
    gemm_mfma<64><<<(N + 63) / 64, 256, 0, stream>>>(hs, whi2, wlo2, xwb, N);
    agg_l2<<<(N + 31) / 32, 256, 0, stream>>>(xwb, csrw, ptr, dis, b2, out, N);
}